// Round 2
// baseline (620.951 us; speedup 1.0000x reference)
//
#include <hip/hip_runtime.h>

#define B_ 4
#define N_ 16384
#define DIN_ 512
#define H_ 8
#define DH_ 64
#define M_ 32
#define HM_ 256
#define INNER_ 512

typedef _Float16 fp16_t;
typedef _Float16 h8 __attribute__((ext_vector_type(8)));
typedef _Float16 h4 __attribute__((ext_vector_type(4)));
typedef float f4 __attribute__((ext_vector_type(4)));

// XOR swizzle of hm (in 8-elem groups) by n-group, keeps w_t transposed LDS reads ~2-way
__device__ __forceinline__ int swz(int n, int hm) {
  return ((((hm >> 3) ^ ((n >> 3) & 3)) << 3) | (hm & 7));
}

// ---------------- K0: composite logit weights  Wcomp[hm,k] = (Wslice @ Wx_h)/temp ----
__global__ __launch_bounds__(256) void k0_prep(
    const float* __restrict__ Wx, const float* __restrict__ bx,
    const float* __restrict__ Wslice, const float* __restrict__ bslice,
    const float* __restrict__ temperature,
    fp16_t* __restrict__ Wcomp, float* __restrict__ bcomp) {
  __shared__ float ws[M_ * DH_];
  const int h = blockIdx.x;
  const int tid = threadIdx.x;
  for (int i = tid; i < M_ * DH_; i += 256) ws[i] = Wslice[i];
  __syncthreads();
  const float invt = 1.0f / temperature[h];
  for (int m = 0; m < M_; ++m) {
    for (int k = tid; k < DIN_; k += 256) {
      float acc = 0.f;
      #pragma unroll 16
      for (int d = 0; d < DH_; ++d)
        acc += ws[m * DH_ + d] * Wx[(size_t)(h * DH_ + d) * DIN_ + k];
      Wcomp[(h * M_ + m) * DIN_ + k] = (fp16_t)(acc * invt);
    }
  }
  if (tid < M_) {
    const int m = tid;
    float acc = bslice[m];
    for (int d = 0; d < DH_; ++d) acc += ws[m * DH_ + d] * bx[h * DH_ + d];
    bcomp[h * M_ + m] = acc * invt;
  }
}

// ---------------- K1: logits GEMM + softmax over M ----------------------------------
// writes w [b][n][hm] (for K4) AND w_t [b][hm][n] (for K2). No atomics, no shfl chains.
__global__ __launch_bounds__(256) void k1_logits(
    const float* __restrict__ x, const fp16_t* __restrict__ Wcomp,
    const float* __restrict__ bcomp, fp16_t* __restrict__ wout,
    fp16_t* __restrict__ w_t) {
  __shared__ __align__(16) fp16_t smem[16896];   // 33792 B, aliased
  fp16_t* lx = smem;            // [64 n][32 k] stride 40  (2560)
  fp16_t* lw = smem + 2560;     // [256 hm][32 k] stride 40 (10240)
  fp16_t* lt = smem;            // [64 n][264 hm-swizzled] epilogue tile (16896)
  const int tid = threadIdx.x;
  const int lane = tid & 63;
  const int wv = tid >> 6;
  const int n0 = blockIdx.x * 64;
  const int b = blockIdx.y;
  f4 acc[4][4] = {};
  const float* xb = x + ((size_t)b * N_ + n0) * DIN_;
  const int lrow = lane & 15;
  const int kb = (lane >> 4) * 8;

  for (int kt = 0; kt < DIN_ / 32; ++kt) {
    const int k0 = kt * 32;
    #pragma unroll
    for (int i = 0; i < 2; ++i) {
      const int id = tid + i * 256;
      const int row = id >> 3, q = id & 7;
      f4 v = *(const f4*)(xb + (size_t)row * DIN_ + k0 + q * 4);
      h4 hv = {(fp16_t)v.x, (fp16_t)v.y, (fp16_t)v.z, (fp16_t)v.w};
      *(h4*)&lx[row * 40 + q * 4] = hv;
    }
    #pragma unroll
    for (int i = 0; i < 4; ++i) {
      const int id = tid + i * 256;
      const int row = id >> 2, q = id & 3;
      *(h8*)&lw[row * 40 + q * 8] = *(const h8*)(Wcomp + (size_t)row * DIN_ + k0 + q * 8);
    }
    __syncthreads();
    h8 af[4], bf[4];
    #pragma unroll
    for (int t = 0; t < 4; ++t) af[t] = *(const h8*)&lx[(t * 16 + lrow) * 40 + kb];
    #pragma unroll
    for (int t = 0; t < 4; ++t) bf[t] = *(const h8*)&lw[(wv * 64 + t * 16 + lrow) * 40 + kb];
    #pragma unroll
    for (int tn = 0; tn < 4; ++tn)
      #pragma unroll
      for (int tc = 0; tc < 4; ++tc)
        acc[tn][tc] = __builtin_amdgcn_mfma_f32_16x16x32_f16(af[tn], bf[tc], acc[tn][tc], 0, 0, 0);
    __syncthreads();
  }

  // ---- epilogue: bias-add, dump logits to LDS tile [n][hm] (swizzled) ----
  const int col = lane & 15;
  const int rgrp = (lane >> 4) * 4;
  float bc[2][2];
  #pragma unroll
  for (int s = 0; s < 2; ++s) {
    bc[s][0] = bcomp[wv * 64 + s * 32 + col];
    bc[s][1] = bcomp[wv * 64 + s * 32 + 16 + col];
  }
  #pragma unroll
  for (int s = 0; s < 2; ++s) {
    const int hmA = wv * 64 + s * 32 + col;
    #pragma unroll
    for (int tn = 0; tn < 4; ++tn)
      #pragma unroll
      for (int r = 0; r < 4; ++r) {
        const int nl = tn * 16 + rgrp + r;
        lt[nl * 264 + swz(nl, hmA)] = (fp16_t)(acc[tn][2 * s][r] + bc[s][0]);
        lt[nl * 264 + swz(nl, hmA + 16)] = (fp16_t)(acc[tn][2 * s + 1][r] + bc[s][1]);
      }
  }
  __syncthreads();

  // ---- softmax: each thread owns one (n, head) row of 32 logits ----
  #pragma unroll
  for (int p = 0; p < 2; ++p) {
    const int pair = tid + p * 256;
    const int nl = pair >> 3, h = pair & 7;
    const int sw = (nl >> 3) & 3;
    h8 ch[4];
    #pragma unroll
    for (int q = 0; q < 4; ++q)
      ch[q] = *(const h8*)&lt[nl * 264 + ((h * 4 + q) ^ sw) * 8];
    float v[32];
    #pragma unroll
    for (int q = 0; q < 4; ++q)
      #pragma unroll
      for (int e = 0; e < 8; ++e) v[q * 8 + e] = (float)ch[q][e];
    float mx = v[0];
    #pragma unroll
    for (int j = 1; j < 32; ++j) mx = fmaxf(mx, v[j]);
    float sm = 0.f;
    #pragma unroll
    for (int j = 0; j < 32; ++j) { v[j] = __expf(v[j] - mx); sm += v[j]; }
    const float inv = __builtin_amdgcn_rcpf(sm);
    h8 oc[4];
    #pragma unroll
    for (int q = 0; q < 4; ++q)
      #pragma unroll
      for (int e = 0; e < 8; ++e) oc[q][e] = (fp16_t)(v[q * 8 + e] * inv);
    fp16_t* gw = wout + ((size_t)b * N_ + n0 + nl) * HM_ + h * 32;
    #pragma unroll
    for (int q = 0; q < 4; ++q) {
      *(h8*)(gw + q * 8) = oc[q];                              // coalesced n-major w
      *(h8*)&lt[nl * 264 + ((h * 4 + q) ^ sw) * 8] = oc[q];    // back to LDS for w_t
    }
  }
  __syncthreads();

  // ---- w_t pass: transposed LDS reads -> coalesced hm-major global writes ----
  #pragma unroll
  for (int pass = 0; pass < 8; ++pass) {
    const int hm = pass * 32 + (tid >> 3);
    const int c = tid & 7;
    h8 buf;
    #pragma unroll
    for (int j = 0; j < 8; ++j) {
      const int n = c * 8 + j;
      buf[j] = lt[n * 264 + swz(n, hm)];
    }
    *(h8*)(w_t + ((size_t)(b * HM_ + hm)) * N_ + n0 + c * 8) = buf;
  }
}

// ---------------- K2: S[b,hm,k] = sum_n w[b,n,hm] * x[b,n,k]  (split-K over n) ------
// grid.x: 8 = (hm-tile 2) x (k-tile 4); grid.y: 32 n-chunks of 512; grid.z: b
// also computes norm[b,hm] = sum_n w (on k-tile-0 blocks, from the staged w_t tile)
__global__ __launch_bounds__(256) void k2_S(
    const float* __restrict__ x, const fp16_t* __restrict__ w_t,
    float* __restrict__ S, float* __restrict__ norm) {
  __shared__ fp16_t lw[128 * 40];   // w_t tile [hm][32 n]
  __shared__ fp16_t lxk[128 * 40];  // x^T tile [k][32 n]
  const int tid = threadIdx.x, lane = tid & 63, wv = tid >> 6;
  const int hm0 = (blockIdx.x & 1) * 128;
  const int kc0 = (blockIdx.x >> 1) * 128;
  const int nbeg = blockIdx.y * 512;
  const int b = blockIdx.z;
  f4 acc[4][4] = {};
  const fp16_t* wtb = w_t + (size_t)(b * HM_ + hm0) * N_;
  const float* xb = x + (size_t)b * N_ * DIN_;
  const int cidx = tid & 127;
  const int ng = (tid >> 7) * 16;
  const int lr = lane & 15;
  const int kb = (lane >> 4) * 8;
  const int hmw = (wv & 1) * 64, kw = (wv >> 1) * 64;
  const bool do_norm = (kc0 == 0);
  float nsum0 = 0.f, nsum1 = 0.f;

  for (int it = 0; it < 16; ++it) {
    const int nn = nbeg + it * 32;
    // w_t staging: natural h8 loads
    {
      const int row0 = tid >> 2, q0 = tid & 3;
      h8 v0 = *(const h8*)(wtb + (size_t)row0 * N_ + nn + q0 * 8);
      *(h8*)&lw[row0 * 40 + q0 * 8] = v0;
      h8 v1 = *(const h8*)(wtb + (size_t)(row0 + 64) * N_ + nn + q0 * 8);
      *(h8*)&lw[(row0 + 64) * 40 + q0 * 8] = v1;
      if (do_norm) {
        #pragma unroll
        for (int e = 0; e < 8; ++e) { nsum0 += (float)v0[e]; nsum1 += (float)v1[e]; }
      }
    }
    // x staging: transposed gather + fp16 convert
    {
      alignas(16) fp16_t tx[16];
      #pragma unroll
      for (int j = 0; j < 16; ++j)
        tx[j] = (fp16_t)xb[(size_t)(nn + ng + j) * DIN_ + kc0 + cidx];
      *(h8*)&lxk[cidx * 40 + ng] = *(h8*)&tx[0];
      *(h8*)&lxk[cidx * 40 + ng + 8] = *(h8*)&tx[8];
    }
    __syncthreads();
    h8 af[4], bf[4];
    #pragma unroll
    for (int t = 0; t < 4; ++t) af[t] = *(const h8*)&lw[(hmw + t * 16 + lr) * 40 + kb];
    #pragma unroll
    for (int t = 0; t < 4; ++t) bf[t] = *(const h8*)&lxk[(kw + t * 16 + lr) * 40 + kb];
    #pragma unroll
    for (int tn = 0; tn < 4; ++tn)
      #pragma unroll
      for (int tc = 0; tc < 4; ++tc)
        acc[tn][tc] = __builtin_amdgcn_mfma_f32_16x16x32_f16(af[tn], bf[tc], acc[tn][tc], 0, 0, 0);
    __syncthreads();
  }

  if (do_norm) {
    nsum0 += __shfl_xor(nsum0, 1); nsum0 += __shfl_xor(nsum0, 2);
    nsum1 += __shfl_xor(nsum1, 1); nsum1 += __shfl_xor(nsum1, 2);
    if ((tid & 3) == 0) {
      atomicAdd(&norm[b * HM_ + hm0 + (tid >> 2)], nsum0);
      atomicAdd(&norm[b * HM_ + hm0 + (tid >> 2) + 64], nsum1);
    }
  }
  const int rg = (lane >> 4) * 4;
  #pragma unroll
  for (int tn = 0; tn < 4; ++tn)
    #pragma unroll
    for (int tc = 0; tc < 4; ++tc)
      #pragma unroll
      for (int r = 0; r < 4; ++r) {
        const int hm = hm0 + hmw + tn * 16 + rg + r;
        const int k = kc0 + kw + tc * 16 + lr;
        atomicAdd(&S[((size_t)b * HM_ + hm) * DIN_ + k], acc[tn][tc][r]);
      }
}

// ---------------- K3a: slice_token[b,h,m,d] = (S.Wfx + bfx*norm)/(norm+1e-5) --------
__global__ __launch_bounds__(256) void k3a_st(
    const float* __restrict__ S, const float* __restrict__ Wfx,
    const float* __restrict__ bfx, const float* __restrict__ norm,
    float* __restrict__ st) {
  const int mq = blockIdx.x;
  const int h = blockIdx.y;
  const int b = blockIdx.z;
  const int tid = threadIdx.x;
  const int m = mq * 4 + (tid >> 6);
  const int d = tid & 63;
  const float* sr = S + ((size_t)b * HM_ + h * M_ + m) * DIN_;
  const float* wr = Wfx + (size_t)(h * DH_ + d) * DIN_;
  float acc = 0.f;
  #pragma unroll 8
  for (int k = 0; k < DIN_; k += 4) {
    f4 a = *(const f4*)(sr + k);
    f4 bb = *(const f4*)(wr + k);
    acc += a.x * bb.x + a.y * bb.y + a.z * bb.z + a.w * bb.w;
  }
  const float nr = norm[b * HM_ + h * M_ + m];
  st[(((size_t)b * H_ + h) * M_ + m) * DH_ + d] =
      (acc + bfx[h * DH_ + d] * nr) / (nr + 1e-5f);
}

// ---------------- K3b: tiny M=32 attention per (b,h) --------------------------------
__global__ __launch_bounds__(256) void k3b_attn(
    const float* __restrict__ st_g, const float* __restrict__ Wq,
    const float* __restrict__ Wk, const float* __restrict__ Wv,
    float* __restrict__ os_g) {
  __shared__ float st[32][65], qs[32][65], ks[32][65], vs[32][65], at[32][33];
  const int h = blockIdx.x, b = blockIdx.y, tid = threadIdx.x;
  const float* stp = st_g + ((size_t)b * H_ + h) * M_ * DH_;
  for (int i = tid; i < 2048; i += 256) st[i >> 6][i & 63] = stp[i];
  __syncthreads();
  for (int i = tid; i < 2048; i += 256) {
    const int m = i >> 6, d = i & 63;
    float aq = 0, ak = 0, av = 0;
    #pragma unroll 8
    for (int dd = 0; dd < 64; ++dd) {
      const float s = st[m][dd];
      aq += s * Wq[d * 64 + dd];
      ak += s * Wk[d * 64 + dd];
      av += s * Wv[d * 64 + dd];
    }
    qs[m][d] = aq; ks[m][d] = ak; vs[m][d] = av;
  }
  __syncthreads();
  for (int i = tid; i < 1024; i += 256) {
    const int m = i >> 5, j = i & 31;
    float a = 0;
    #pragma unroll 8
    for (int d = 0; d < 64; ++d) a += qs[m][d] * ks[j][d];
    at[m][j] = a * 0.125f;
  }
  __syncthreads();
  if (tid < 32) {
    const int m = tid;
    float mx = -1e30f;
    for (int j = 0; j < 32; ++j) mx = fmaxf(mx, at[m][j]);
    float sm = 0;
    for (int j = 0; j < 32; ++j) { const float e = __expf(at[m][j] - mx); at[m][j] = e; sm += e; }
    const float inv = 1.0f / sm;
    for (int j = 0; j < 32; ++j) at[m][j] *= inv;
  }
  __syncthreads();
  float* osp = os_g + ((size_t)b * H_ + h) * M_ * DH_;
  for (int i = tid; i < 2048; i += 256) {
    const int m = i >> 6, d = i & 63;
    float a = 0;
    #pragma unroll 8
    for (int j = 0; j < 32; ++j) a += at[m][j] * vs[j][d];
    osp[i] = a;
  }
}

// ---------------- K3c: Ct[b,kk,hm] = sum_d os[b,h,m,d] * Wout[kk, h*64+d] -----------
__global__ __launch_bounds__(256) void k3c_ct(
    const float* __restrict__ os_g, const float* __restrict__ Wout,
    fp16_t* __restrict__ Ct) {
  const int kc = blockIdx.x;
  const int b = blockIdx.y;
  const int tid = threadIdx.x;
  #pragma unroll
  for (int i = 0; i < 16; ++i) {
    const int idx = tid + i * 256;
    const int hm = idx & 255, kkl = idx >> 8;
    const int kk = kc * 16 + kkl;
    const int h = hm >> 5, m = hm & 31;
    const float* op = os_g + (((size_t)b * H_ + h) * M_ + m) * DH_;
    const float* wp = Wout + (size_t)kk * INNER_ + h * DH_;
    float acc = 0.f;
    #pragma unroll
    for (int d = 0; d < 64; d += 4) {
      f4 a = *(const f4*)(op + d);
      f4 w4 = *(const f4*)(wp + d);
      acc += a.x * w4.x + a.y * w4.y + a.z * w4.z + a.w * w4.w;
    }
    Ct[((size_t)b * DIN_ + kk) * HM_ + hm] = (fp16_t)acc;
  }
}

// ---------------- K4: out[b,n,kk] = w[b,n,:] . Ct[b,kk,:] + bout[kk] ----------------
__global__ __launch_bounds__(256) void k4_out(
    const fp16_t* __restrict__ w, const fp16_t* __restrict__ Ct,
    const float* __restrict__ bout, float* __restrict__ out) {
  __shared__ fp16_t la[128 * 40];
  __shared__ fp16_t lb[128 * 40];
  const int tid = threadIdx.x, lane = tid & 63, wv = tid >> 6;
  const int kk0 = blockIdx.x * 128;
  const int n0 = blockIdx.y * 128;
  const int b = blockIdx.z;
  f4 acc[4][4] = {};
  const fp16_t* wb = w + ((size_t)b * N_ + n0) * HM_;
  const fp16_t* cb = Ct + ((size_t)b * DIN_ + kk0) * HM_;
  const int lr = lane & 15;
  const int kb = (lane >> 4) * 8;
  const int nh = (wv & 1) * 64, kh = (wv >> 1) * 64;

  for (int kt = 0; kt < HM_ / 32; ++kt) {
    const int k0 = kt * 32;
    #pragma unroll
    for (int i = 0; i < 2; ++i) {
      const int id = tid + i * 256;
      const int row = id >> 2, q = id & 3;
      *(h8*)&la[row * 40 + q * 8] = *(const h8*)(wb + (size_t)row * HM_ + k0 + q * 8);
    }
    #pragma unroll
    for (int i = 0; i < 2; ++i) {
      const int id = tid + i * 256;
      const int row = id >> 2, q = id & 3;
      *(h8*)&lb[row * 40 + q * 8] = *(const h8*)(cb + (size_t)row * HM_ + k0 + q * 8);
    }
    __syncthreads();
    h8 af[4], bf[4];
    #pragma unroll
    for (int t = 0; t < 4; ++t) af[t] = *(const h8*)&la[(nh + t * 16 + lr) * 40 + kb];
    #pragma unroll
    for (int t = 0; t < 4; ++t) bf[t] = *(const h8*)&lb[(kh + t * 16 + lr) * 40 + kb];
    #pragma unroll
    for (int tn = 0; tn < 4; ++tn)
      #pragma unroll
      for (int tc = 0; tc < 4; ++tc)
        acc[tn][tc] = __builtin_amdgcn_mfma_f32_16x16x32_f16(af[tn], bf[tc], acc[tn][tc], 0, 0, 0);
    __syncthreads();
  }
  const int rg = (lane >> 4) * 4;
  #pragma unroll
  for (int tc = 0; tc < 4; ++tc) {
    const int kk = kk0 + kh + tc * 16 + lr;
    const float bo = bout[kk];
    #pragma unroll
    for (int tn = 0; tn < 4; ++tn)
      #pragma unroll
      for (int r = 0; r < 4; ++r) {
        const int n = n0 + nh + tn * 16 + rg + r;
        out[((size_t)b * N_ + n) * DIN_ + kk] = acc[tn][tc][r] + bo;
      }
  }
}

extern "C" void kernel_launch(void* const* d_in, const int* in_sizes, int n_in,
                              void* d_out, int out_size, void* d_ws, size_t ws_size,
                              hipStream_t stream) {
  (void)in_sizes; (void)n_in; (void)out_size; (void)ws_size;
  const float* x       = (const float*)d_in[0];
  const float* Wx      = (const float*)d_in[1];
  const float* bx      = (const float*)d_in[2];
  const float* Wfx     = (const float*)d_in[3];
  const float* bfx     = (const float*)d_in[4];
  const float* Wslice  = (const float*)d_in[5];
  const float* bslice  = (const float*)d_in[6];
  const float* Wq      = (const float*)d_in[7];
  const float* Wk      = (const float*)d_in[8];
  const float* Wv      = (const float*)d_in[9];
  const float* Wout    = (const float*)d_in[10];
  const float* bout    = (const float*)d_in[11];
  const float* temp    = (const float*)d_in[12];
  float* out = (float*)d_out;

  char* ws = (char*)d_ws;
  fp16_t* wbuf  = (fp16_t*)ws;                    // 33,554,432 : w   [B][N][256] fp16
  fp16_t* w_t   = (fp16_t*)(ws + 33554432);       // 33,554,432 : w_t [B][256][N] fp16
  float*  S     = (float*)(ws + 67108864);        //  2,097,152 : S [B][256][512] f32
  float*  norm  = (float*)(ws + 69206016);        //      4,096
  float*  st    = (float*)(ws + 69210112);        //    262,144
  float*  os    = (float*)(ws + 69472256);        //    262,144
  fp16_t* Ct    = (fp16_t*)(ws + 69734400);       //  1,048,576
  fp16_t* Wcomp = (fp16_t*)(ws + 70782976);       //    262,144
  float*  bcomp = (float*)(ws + 71045120);        //      1,024

  hipMemsetAsync(S, 0, (size_t)B_ * HM_ * DIN_ * 4, stream);
  hipMemsetAsync(norm, 0, (size_t)B_ * HM_ * 4, stream);
  k0_prep<<<dim3(H_), 256, 0, stream>>>(Wx, bx, Wslice, bslice, temp, Wcomp, bcomp);
  k1_logits<<<dim3(N_ / 64, B_), 256, 0, stream>>>(x, Wcomp, bcomp, wbuf, w_t);
  k2_S<<<dim3(8, 32, B_), 256, 0, stream>>>(x, w_t, S, norm);
  k3a_st<<<dim3(8, H_, B_), 256, 0, stream>>>(S, Wfx, bfx, norm, st);
  k3b_attn<<<dim3(H_, B_), 256, 0, stream>>>(st, Wq, Wk, Wv, os);
  k3c_ct<<<dim3(32, B_), 256, 0, stream>>>(os, Wout, Ct);
  k4_out<<<dim3(DIN_ / 128, N_ / 128, B_), 256, 0, stream>>>(wbuf, Ct, bout, out);
}

// Round 3
// 553.956 us; speedup vs baseline: 1.1209x; 1.1209x over previous
//
#include <hip/hip_runtime.h>

#define B_ 4
#define N_ 16384
#define DIN_ 512
#define H_ 8
#define DH_ 64
#define M_ 32
#define HM_ 256
#define INNER_ 512

typedef _Float16 fp16_t;
typedef _Float16 h8 __attribute__((ext_vector_type(8)));
typedef _Float16 h4 __attribute__((ext_vector_type(4)));
typedef float f4 __attribute__((ext_vector_type(4)));

// Fragment-blocked layout: a logical operand Q[R rows][K contraction] is stored as
// tiles of 16 rows x 32 k; tile -> 512 fp16; element (row, k) at lane*8+e where
// lane = (k%32/8)*16 + row%16, e = k%8. A wave reads one fragment as ONE h8 load
// at (tile_base + lane*8) -- perfectly coalesced 1KB, zero LDS, zero barriers.

// XOR swizzle of hm (in 8-elem groups) by n-group for the K1 epilogue LDS tile
__device__ __forceinline__ int swz(int n, int hm) {
  return ((((hm >> 3) ^ ((n >> 3) & 3)) << 3) | (hm & 7));
}

// ---------------- K0: composite logit weights  Wcomp[hm,k] = (Wslice @ Wx_h)/temp ----
__global__ __launch_bounds__(256) void k0_prep(
    const float* __restrict__ Wx, const float* __restrict__ bx,
    const float* __restrict__ Wslice, const float* __restrict__ bslice,
    const float* __restrict__ temperature,
    fp16_t* __restrict__ Wcomp, float* __restrict__ bcomp) {
  __shared__ float ws[M_ * DH_];
  const int h = blockIdx.x;
  const int tid = threadIdx.x;
  for (int i = tid; i < M_ * DH_; i += 256) ws[i] = Wslice[i];
  __syncthreads();
  const float invt = 1.0f / temperature[h];
  for (int m = 0; m < M_; ++m) {
    for (int k = tid; k < DIN_; k += 256) {
      float acc = 0.f;
      #pragma unroll 16
      for (int d = 0; d < DH_; ++d)
        acc += ws[m * DH_ + d] * Wx[(size_t)(h * DH_ + d) * DIN_ + k];
      Wcomp[(h * M_ + m) * DIN_ + k] = (fp16_t)(acc * invt);
    }
  }
  if (tid < M_) {
    const int m = tid;
    float acc = bslice[m];
    for (int d = 0; d < DH_; ++d) acc += ws[m * DH_ + d] * bx[h * DH_ + d];
    bcomp[h * M_ + m] = acc * invt;
  }
}

// ---------------- K1: logits GEMM + softmax; emits w_blk, wt_blk, xt_blk ------------
// w_blk : w  [b][nt=N/16][hmb=8][512]    (K4 A-operand)
// wt_blk: w^T[b][hmt=16][nt=N/32][512]   (K2 A-operand)
// xt_blk: x^T[b][kt=32][nt=N/32][512]    (K2 B-operand, fp16)
__global__ __launch_bounds__(256) void k1_logits(
    const float* __restrict__ x, const fp16_t* __restrict__ Wcomp,
    const float* __restrict__ bcomp, fp16_t* __restrict__ w_blk,
    fp16_t* __restrict__ wt_blk, fp16_t* __restrict__ xt_blk) {
  __shared__ __align__(16) fp16_t smem[16896];   // 33792 B, aliased
  fp16_t* lx = smem;            // [64 n][32 k] stride 40
  fp16_t* lw = smem + 2560;     // [256 hm][32 k] stride 40
  fp16_t* lt = smem;            // [64 n][264 hm-swizzled] epilogue tile
  const int tid = threadIdx.x;
  const int lane = tid & 63;
  const int wv = tid >> 6;
  const int n0 = blockIdx.x * 64;
  const int b = blockIdx.y;
  f4 acc[4][4] = {};
  const float* xb = x + ((size_t)b * N_ + n0) * DIN_;
  const int lrow = lane & 15;
  const int kb = (lane >> 4) * 8;
  // xt-pass constants: this thread owns chunk (rt, nt) of the 32k x 64n iter tile
  const int xt_rt = wv >> 1;                    // 0..1  (k sub-tile of 16)
  const int xt_nt = wv & 1;                     // 0..1  (n sub-tile of 32)
  const int xt_k = xt_rt * 16 + (lane & 15);
  const int xt_nb = xt_nt * 32 + (lane >> 4) * 8;

  for (int kt = 0; kt < DIN_ / 32; ++kt) {
    const int k0 = kt * 32;
    #pragma unroll
    for (int i = 0; i < 2; ++i) {
      const int id = tid + i * 256;
      const int row = id >> 3, q = id & 7;
      f4 v = *(const f4*)(xb + (size_t)row * DIN_ + k0 + q * 4);
      h4 hv = {(fp16_t)v.x, (fp16_t)v.y, (fp16_t)v.z, (fp16_t)v.w};
      *(h4*)&lx[row * 40 + q * 4] = hv;
    }
    #pragma unroll
    for (int i = 0; i < 4; ++i) {
      const int id = tid + i * 256;
      const int row = id >> 2, q = id & 3;
      *(h8*)&lw[row * 40 + q * 8] = *(const h8*)(Wcomp + (size_t)row * DIN_ + k0 + q * 8);
    }
    __syncthreads();
    // emit xt_blk chunk for this iter (reads lx, safe until next staging sync)
    {
      h8 tx;
      #pragma unroll
      for (int e = 0; e < 8; ++e) tx[e] = lx[(xt_nb + e) * 40 + xt_k];
      *(h8*)(xt_blk + (((size_t)(b * 32 + kt * 2 + xt_rt) * (N_ / 32)) + (n0 >> 5) + xt_nt) * 512 + lane * 8) = tx;
    }
    h8 af[4], bf[4];
    #pragma unroll
    for (int t = 0; t < 4; ++t) af[t] = *(const h8*)&lx[(t * 16 + lrow) * 40 + kb];
    #pragma unroll
    for (int t = 0; t < 4; ++t) bf[t] = *(const h8*)&lw[(wv * 64 + t * 16 + lrow) * 40 + kb];
    #pragma unroll
    for (int tn = 0; tn < 4; ++tn)
      #pragma unroll
      for (int tc = 0; tc < 4; ++tc)
        acc[tn][tc] = __builtin_amdgcn_mfma_f32_16x16x32_f16(af[tn], bf[tc], acc[tn][tc], 0, 0, 0);
    __syncthreads();
  }

  // ---- epilogue: bias-add, dump logits to LDS tile [n][hm] (swizzled) ----
  const int col = lane & 15;
  const int rgrp = (lane >> 4) * 4;
  float bc[2][2];
  #pragma unroll
  for (int s = 0; s < 2; ++s) {
    bc[s][0] = bcomp[wv * 64 + s * 32 + col];
    bc[s][1] = bcomp[wv * 64 + s * 32 + 16 + col];
  }
  #pragma unroll
  for (int s = 0; s < 2; ++s) {
    const int hmA = wv * 64 + s * 32 + col;
    #pragma unroll
    for (int tn = 0; tn < 4; ++tn)
      #pragma unroll
      for (int r = 0; r < 4; ++r) {
        const int nl = tn * 16 + rgrp + r;
        lt[nl * 264 + swz(nl, hmA)] = (fp16_t)(acc[tn][2 * s][r] + bc[s][0]);
        lt[nl * 264 + swz(nl, hmA + 16)] = (fp16_t)(acc[tn][2 * s + 1][r] + bc[s][1]);
      }
  }
  __syncthreads();

  // ---- softmax: each thread owns one (n, head) row of 32 logits ----
  #pragma unroll
  for (int p = 0; p < 2; ++p) {
    const int pair = tid + p * 256;
    const int nl = pair >> 3, h = pair & 7;
    const int sw = (nl >> 3) & 3;
    h8 ch[4];
    #pragma unroll
    for (int q = 0; q < 4; ++q)
      ch[q] = *(const h8*)&lt[nl * 264 + ((h * 4 + q) ^ sw) * 8];
    float v[32];
    #pragma unroll
    for (int q = 0; q < 4; ++q)
      #pragma unroll
      for (int e = 0; e < 8; ++e) v[q * 8 + e] = (float)ch[q][e];
    float mx = v[0];
    #pragma unroll
    for (int j = 1; j < 32; ++j) mx = fmaxf(mx, v[j]);
    float sm = 0.f;
    #pragma unroll
    for (int j = 0; j < 32; ++j) { v[j] = __expf(v[j] - mx); sm += v[j]; }
    const float inv = __builtin_amdgcn_rcpf(sm);
    h8 oc[4];
    #pragma unroll
    for (int q = 0; q < 4; ++q)
      #pragma unroll
      for (int e = 0; e < 8; ++e) oc[q][e] = (fp16_t)(v[q * 8 + e] * inv);
    #pragma unroll
    for (int q = 0; q < 4; ++q)
      *(h8*)&lt[nl * 264 + ((h * 4 + q) ^ sw) * 8] = oc[q];
  }
  __syncthreads();

  // ---- w_blk pass: contiguous h8 LDS reads -> blocked global (K4 A layout) ----
  #pragma unroll
  for (int p = 0; p < 8; ++p) {
    const int tile = p * 4 + wv;          // 0..31 = 4 ntiles x 8 hmblks
    const int nt_l = tile >> 3, hmb = tile & 7;
    const int n_l = nt_l * 16 + (lane & 15);
    const int g = hmb * 4 + (lane >> 4);
    const int sw = (n_l >> 3) & 3;
    h8 v = *(const h8*)&lt[n_l * 264 + (g ^ sw) * 8];
    *(h8*)(w_blk + (((size_t)(b * (N_ / 16) + (n0 >> 4) + nt_l)) * 8 + hmb) * 512 + lane * 8) = v;
  }

  // ---- wt_blk pass: strided LDS gather -> blocked global (K2 A layout) ----
  #pragma unroll
  for (int p = 0; p < 8; ++p) {
    const int tile = p * 4 + wv;          // 0..31 = 16 hmtiles x 2 ntiles
    const int hmt = tile >> 1, ntl = tile & 1;
    const int hm = hmt * 16 + (lane & 15);
    const int nb = ntl * 32 + (lane >> 4) * 8;
    h8 v;
    #pragma unroll
    for (int e = 0; e < 8; ++e) {
      const int n = nb + e;
      v[e] = lt[n * 264 + swz(n, hm)];
    }
    *(h8*)(wt_blk + (((size_t)(b * 16 + hmt)) * (N_ / 32) + (n0 >> 5) + ntl) * 512 + lane * 8) = v;
  }
}

// ---------------- K2: S[b,hm,k] = sum_n w^T x  — barrier-free streaming MFMA --------
// grid.x: 8 = (hm-tile 2) x (k-tile 4); grid.y: 32 n-chunks of 512; grid.z: b
__global__ __launch_bounds__(256) void k2_S(
    const fp16_t* __restrict__ wt_blk, const fp16_t* __restrict__ xt_blk,
    float* __restrict__ S, float* __restrict__ norm) {
  const int tid = threadIdx.x, lane = tid & 63, wv = tid >> 6;
  const int hm0 = (blockIdx.x & 1) * 128;
  const int kc0 = (blockIdx.x >> 1) * 128;
  const int nt0 = blockIdx.y * 16;            // 512 n = 16 n-tiles of 32
  const int b = blockIdx.z;
  const int hmw = (wv & 1) * 64, kw = (wv >> 1) * 64;
  const int hmt0 = (hm0 + hmw) >> 4;
  const int kt0 = (kc0 + kw) >> 4;
  const fp16_t* ap = wt_blk + (((size_t)(b * 16 + hmt0)) * (N_ / 32) + nt0) * 512 + lane * 8;
  const fp16_t* bp = xt_blk + (((size_t)(b * 32 + kt0)) * (N_ / 32) + nt0) * 512 + lane * 8;
  const size_t arow = (size_t)(N_ / 32) * 512;  // stride between row-tiles
  f4 acc[4][4] = {};
  float ns[4] = {0.f, 0.f, 0.f, 0.f};
  const bool do_norm = (kc0 == 0) && (kw == 0);

  for (int it = 0; it < 16; ++it) {
    h8 af[4], bf[4];
    #pragma unroll
    for (int t = 0; t < 4; ++t) af[t] = *(const h8*)(ap + (size_t)t * arow + it * 512);
    #pragma unroll
    for (int t = 0; t < 4; ++t) bf[t] = *(const h8*)(bp + (size_t)t * arow + it * 512);
    #pragma unroll
    for (int tn = 0; tn < 4; ++tn)
      #pragma unroll
      for (int tc = 0; tc < 4; ++tc)
        acc[tn][tc] = __builtin_amdgcn_mfma_f32_16x16x32_f16(af[tn], bf[tc], acc[tn][tc], 0, 0, 0);
    if (do_norm) {
      #pragma unroll
      for (int t = 0; t < 4; ++t)
        #pragma unroll
        for (int e = 0; e < 8; ++e) ns[t] += (float)af[t][e];
    }
  }

  if (do_norm) {
    #pragma unroll
    for (int t = 0; t < 4; ++t) {
      ns[t] += __shfl_xor(ns[t], 16);
      ns[t] += __shfl_xor(ns[t], 32);
    }
    if (lane < 16) {
      #pragma unroll
      for (int t = 0; t < 4; ++t)
        atomicAdd(&norm[b * HM_ + (hmt0 + t) * 16 + lane], ns[t]);
    }
  }
  const int rg = (lane >> 4) * 4;
  #pragma unroll
  for (int tn = 0; tn < 4; ++tn)
    #pragma unroll
    for (int tc = 0; tc < 4; ++tc)
      #pragma unroll
      for (int r = 0; r < 4; ++r) {
        const int hm = hm0 + hmw + tn * 16 + rg + r;
        const int k = kc0 + kw + tc * 16 + (lane & 15);
        atomicAdd(&S[((size_t)b * HM_ + hm) * DIN_ + k], acc[tn][tc][r]);
      }
}

// ---------------- K3a: slice_token[b,h,m,d] = (S.Wfx + bfx*norm)/(norm+1e-5) --------
__global__ __launch_bounds__(256) void k3a_st(
    const float* __restrict__ S, const float* __restrict__ Wfx,
    const float* __restrict__ bfx, const float* __restrict__ norm,
    float* __restrict__ st) {
  const int mq = blockIdx.x;
  const int h = blockIdx.y;
  const int b = blockIdx.z;
  const int tid = threadIdx.x;
  const int m = mq * 4 + (tid >> 6);
  const int d = tid & 63;
  const float* sr = S + ((size_t)b * HM_ + h * M_ + m) * DIN_;
  const float* wr = Wfx + (size_t)(h * DH_ + d) * DIN_;
  float acc = 0.f;
  #pragma unroll 8
  for (int k = 0; k < DIN_; k += 4) {
    f4 a = *(const f4*)(sr + k);
    f4 bb = *(const f4*)(wr + k);
    acc += a.x * bb.x + a.y * bb.y + a.z * bb.z + a.w * bb.w;
  }
  const float nr = norm[b * HM_ + h * M_ + m];
  st[(((size_t)b * H_ + h) * M_ + m) * DH_ + d] =
      (acc + bfx[h * DH_ + d] * nr) / (nr + 1e-5f);
}

// ---------------- K3b: tiny M=32 attention per (b,h) --------------------------------
__global__ __launch_bounds__(256) void k3b_attn(
    const float* __restrict__ st_g, const float* __restrict__ Wq,
    const float* __restrict__ Wk, const float* __restrict__ Wv,
    float* __restrict__ os_g) {
  __shared__ float st[32][65], qs[32][65], ks[32][65], vs[32][65], at[32][33];
  const int h = blockIdx.x, b = blockIdx.y, tid = threadIdx.x;
  const float* stp = st_g + ((size_t)b * H_ + h) * M_ * DH_;
  for (int i = tid; i < 2048; i += 256) st[i >> 6][i & 63] = stp[i];
  __syncthreads();
  for (int i = tid; i < 2048; i += 256) {
    const int m = i >> 6, d = i & 63;
    float aq = 0, ak = 0, av = 0;
    #pragma unroll 8
    for (int dd = 0; dd < 64; ++dd) {
      const float s = st[m][dd];
      aq += s * Wq[d * 64 + dd];
      ak += s * Wk[d * 64 + dd];
      av += s * Wv[d * 64 + dd];
    }
    qs[m][d] = aq; ks[m][d] = ak; vs[m][d] = av;
  }
  __syncthreads();
  for (int i = tid; i < 1024; i += 256) {
    const int m = i >> 5, j = i & 31;
    float a = 0;
    #pragma unroll 8
    for (int d = 0; d < 64; ++d) a += qs[m][d] * ks[j][d];
    at[m][j] = a * 0.125f;
  }
  __syncthreads();
  if (tid < 32) {
    const int m = tid;
    float mx = -1e30f;
    for (int j = 0; j < 32; ++j) mx = fmaxf(mx, at[m][j]);
    float sm = 0;
    for (int j = 0; j < 32; ++j) { const float e = __expf(at[m][j] - mx); at[m][j] = e; sm += e; }
    const float inv = 1.0f / sm;
    for (int j = 0; j < 32; ++j) at[m][j] *= inv;
  }
  __syncthreads();
  float* osp = os_g + ((size_t)b * H_ + h) * M_ * DH_;
  for (int i = tid; i < 2048; i += 256) {
    const int m = i >> 6, d = i & 63;
    float a = 0;
    #pragma unroll 8
    for (int j = 0; j < 32; ++j) a += at[m][j] * vs[j][d];
    osp[i] = a;
  }
}

// ---------------- K3c: Ct_blk[b][kkt=32][hmb=8][512]  (K4 B-operand layout) ---------
__global__ __launch_bounds__(256) void k3c_ct(
    const float* __restrict__ os_g, const float* __restrict__ Wout,
    fp16_t* __restrict__ Ct_blk) {
  const int tid = threadIdx.x, lane = tid & 63, wv = tid >> 6;
  const int b = blockIdx.y;
  const int ti = blockIdx.x * 4 + wv;     // 0..255 tiles
  const int kkt = ti >> 3, hmb = ti & 7;
  const int kk = kkt * 16 + (lane & 15);
  h8 outv;
  #pragma unroll
  for (int e = 0; e < 8; ++e) {
    const int hm = hmb * 32 + (lane >> 4) * 8 + e;
    const int h = hm >> 5, m = hm & 31;
    const float* op = os_g + (((size_t)b * H_ + h) * M_ + m) * DH_;
    const float* wp = Wout + (size_t)kk * INNER_ + h * DH_;
    float acc = 0.f;
    #pragma unroll
    for (int d = 0; d < 64; d += 4) {
      f4 a = *(const f4*)(op + d);
      f4 w4 = *(const f4*)(wp + d);
      acc += a.x * w4.x + a.y * w4.y + a.z * w4.z + a.w * w4.w;
    }
    outv[e] = (fp16_t)acc;
  }
  *(h8*)(Ct_blk + (((size_t)(b * 32 + kkt)) * 8 + hmb) * 512 + lane * 8) = outv;
}

// ---------------- K4: out = w . Ct^T + bout — barrier-free streaming MFMA -----------
// grid: (DIN/128, N/128, B); block 128n x 128kk, wave 64x64
__global__ __launch_bounds__(256) void k4_out(
    const fp16_t* __restrict__ w_blk, const fp16_t* __restrict__ Ct_blk,
    const float* __restrict__ bout, float* __restrict__ out) {
  const int tid = threadIdx.x, lane = tid & 63, wv = tid >> 6;
  const int kk0 = blockIdx.x * 128;
  const int n0 = blockIdx.y * 128;
  const int b = blockIdx.z;
  const int nh = (wv & 1) * 64, kh = (wv >> 1) * 64;
  const int nt0 = (n0 + nh) >> 4;
  const int kkt0 = (kk0 + kh) >> 4;
  const fp16_t* ap = w_blk + ((size_t)(b * (N_ / 16) + nt0)) * 8 * 512 + lane * 8;
  const fp16_t* bp = Ct_blk + ((size_t)(b * 32 + kkt0)) * 8 * 512 + lane * 8;
  f4 acc[4][4] = {};

  #pragma unroll
  for (int hmb = 0; hmb < 8; ++hmb) {
    h8 af[4], bf[4];
    #pragma unroll
    for (int t = 0; t < 4; ++t) af[t] = *(const h8*)(ap + (size_t)t * 8 * 512 + hmb * 512);
    #pragma unroll
    for (int t = 0; t < 4; ++t) bf[t] = *(const h8*)(bp + (size_t)t * 8 * 512 + hmb * 512);
    #pragma unroll
    for (int tn = 0; tn < 4; ++tn)
      #pragma unroll
      for (int tc = 0; tc < 4; ++tc)
        acc[tn][tc] = __builtin_amdgcn_mfma_f32_16x16x32_f16(af[tn], bf[tc], acc[tn][tc], 0, 0, 0);
  }
  const int rg = (lane >> 4) * 4;
  #pragma unroll
  for (int tc = 0; tc < 4; ++tc) {
    const int kk = kk0 + kh + tc * 16 + (lane & 15);
    const float bo = bout[kk];
    #pragma unroll
    for (int tn = 0; tn < 4; ++tn)
      #pragma unroll
      for (int r = 0; r < 4; ++r) {
        const int n = n0 + nh + tn * 16 + rg + r;
        out[((size_t)b * N_ + n) * DIN_ + kk] = acc[tn][tc][r] + bo;
      }
  }
}

extern "C" void kernel_launch(void* const* d_in, const int* in_sizes, int n_in,
                              void* d_out, int out_size, void* d_ws, size_t ws_size,
                              hipStream_t stream) {
  (void)in_sizes; (void)n_in; (void)out_size; (void)ws_size;
  const float* x       = (const float*)d_in[0];
  const float* Wx      = (const float*)d_in[1];
  const float* bx      = (const float*)d_in[2];
  const float* Wfx     = (const float*)d_in[3];
  const float* bfx     = (const float*)d_in[4];
  const float* Wslice  = (const float*)d_in[5];
  const float* bslice  = (const float*)d_in[6];
  const float* Wq      = (const float*)d_in[7];
  const float* Wk      = (const float*)d_in[8];
  const float* Wv      = (const float*)d_in[9];
  const float* Wout    = (const float*)d_in[10];
  const float* bout    = (const float*)d_in[11];
  const float* temp    = (const float*)d_in[12];
  float* out = (float*)d_out;

  char* ws = (char*)d_ws;
  fp16_t* w_blk  = (fp16_t*)ws;                    //  33,554,432 : w  blocked (K4-A)
  fp16_t* wt_blk = (fp16_t*)(ws + 33554432);       //  33,554,432 : w^T blocked (K2-A)
  fp16_t* xt_blk = (fp16_t*)(ws + 67108864);       //  67,108,864 : x^T fp16 blocked (K2-B)
  float*  S      = (float*)(ws + 134217728);       //   2,097,152
  float*  norm   = (float*)(ws + 136314880);       //       4,096
  float*  st     = (float*)(ws + 136318976);       //     262,144
  float*  os     = (float*)(ws + 136581120);       //     262,144
  fp16_t* Ct_blk = (fp16_t*)(ws + 136843264);      //   1,048,576
  fp16_t* Wcomp  = (fp16_t*)(ws + 137891840);      //     262,144
  float*  bcomp  = (float*)(ws + 138153984);       //       1,024

  hipMemsetAsync(S, 0, (size_t)B_ * HM_ * DIN_ * 4, stream);
  hipMemsetAsync(norm, 0, (size_t)B_ * HM_ * 4, stream);
  k0_prep<<<dim3(H_), 256, 0, stream>>>(Wx, bx, Wslice, bslice, temp, Wcomp, bcomp);
  k1_logits<<<dim3(N_ / 64, B_), 256, 0, stream>>>(x, Wcomp, bcomp, w_blk, wt_blk, xt_blk);
  k2_S<<<dim3(8, 32, B_), 256, 0, stream>>>(wt_blk, xt_blk, S, norm);
  k3a_st<<<dim3(8, H_, B_), 256, 0, stream>>>(S, Wfx, bfx, norm, st);
  k3b_attn<<<dim3(H_, B_), 256, 0, stream>>>(st, Wq, Wk, Wv, os);
  k3c_ct<<<dim3(64, B_), 256, 0, stream>>>(os, Wout, Ct_blk);
  k4_out<<<dim3(DIN_ / 128, N_ / 128, B_), 256, 0, stream>>>(w_blk, Ct_blk, bout, out);
}